// Round 5
// baseline (77.149 us; speedup 1.0000x reference)
//
#include <hip/hip_runtime.h>
#include <math.h>

#define B_   2
#define CTX_ 512
#define C_   16
#define RS_  16
#define RT_  16
#define T_   34      // 2 + 2*RT
#define L_   128
#define K_   11
#define H_   1024
#define EPS_ 1e-12f

#define NSPLIT_  16
#define LCHUNK_  8                       // L_ / NSPLIT_
#define NCHUNK_  (T_ * C_ * NSPLIT_)     // 8704
#define NBLK_    512                     // 2 blocks/CU * 256 CU
#define NCHPB_   17                      // NCHUNK_ / NBLK_  (exact)
#define CHUNKB_  (LCHUNK_ * K_ * 128)    // 11264 bytes per A (and per B) slice
#define NLOAD_   22                      // 1KB DMA loads per chunk (11 A + 11 B)
#define NBUF_    3

__device__ __forceinline__ float siglog(float v) {
    return copysignf(log1pf(fabsf(v)), v);
}

__device__ __forceinline__ void gload_lds16(const void* g, void* l) {
    __builtin_amdgcn_global_load_lds(
        (const __attribute__((address_space(1))) unsigned int*)g,
        (__attribute__((address_space(3))) unsigned int*)l, 16, 0, 0);
}

// ---------------- Kernel 1: xt = x@W + b; xm; x2 = (xr+ixi)^2 ----------------
__global__ __launch_bounds__(512) void k_ctx(const float* __restrict__ x,
                                             const float* __restrict__ Wc,
                                             const float* __restrict__ bc,
                                             float2* __restrict__ x2out) {
    __shared__ float xrow[CTX_];
    __shared__ float xt[4 * L_];
    const int b = blockIdx.x;
    const int tid = threadIdx.x;
    xrow[tid] = x[b * CTX_ + tid];
    __syncthreads();
    float sum = bc[tid];
#pragma unroll 8
    for (int c = 0; c < CTX_; ++c)
        sum = fmaf(xrow[c], Wc[c * (4 * L_) + tid], sum);
    xt[tid] = sum;
    __syncthreads();
    if (tid < L_) {
        float xr = xt[2 * tid]     * siglog(xt[2 * L_ + 2 * tid]);
        float xi = xt[2 * tid + 1] * siglog(xt[2 * L_ + 2 * tid + 1]);
        x2out[b * L_ + tid] = make_float2(xr * xr - xi * xi, 2.0f * xr * xi);
    }
}

// ---------------- Kernel 2a: persistent triple-buffered DMA-staged contraction
// 512 blocks x 256 threads; block bk handles chunks bk + i*512, i in [0,17).
// Chunk = (tc = ch>>4, s = ch&15): l in [s*8, s*8+8), all k, all r.
// ONE barrier per iteration; 3 buffers make the buffer-reuse hazard
// barrier-ordered. No cross-wave LDS reduction (each wave atomics its own
// l-quad partial), so no second barrier is needed.
__device__ __forceinline__ void stage_chunk(const char* __restrict__ Ag,
                                            const char* __restrict__ Bg,
                                            int ch, char* dA, char* dB,
                                            int wave, int lane) {
    const int tc = ch >> 4, s = ch & 15;
    const char* Ab = Ag + (size_t)(tc * L_ + s * LCHUNK_) * (K_ * 128);
    const char* Bb = Bg + (size_t)tc * (K_ * L_ * 128) + (size_t)s * (LCHUNK_ * 128);
    for (int id = wave; id < NLOAD_; id += 4) {
        if (id < K_) {
            gload_lds16(Ab + id * 1024 + lane * 16, dA + id * 1024);
        } else {
            const int k = id - K_;
            gload_lds16(Bb + (size_t)k * (L_ * 128) + lane * 16, dB + k * 1024);
        }
    }
}

__global__ __launch_bounds__(256) void k_tr_part(const char* __restrict__ Ag,
                                                 const char* __restrict__ Bg,
                                                 const float2* __restrict__ x2g,
                                                 float* __restrict__ part) {
    __shared__ __attribute__((aligned(16))) char bufA[NBUF_][CHUNKB_];
    __shared__ __attribute__((aligned(16))) char bufB[NBUF_][CHUNKB_];
    __shared__ float2 x2s[B_ * L_];

    const int tid  = threadIdx.x;
    const int wave = tid >> 6;
    const int lane = tid & 63;
    const int bk   = blockIdx.x;
    const int r    = lane & 15;

    // preload x2 (tiny; completes before staging matters)
    x2s[tid] = x2g[tid];
    asm volatile("s_waitcnt lgkmcnt(0)" ::: "memory");

    // prologue: stage chunk 0 into buf 0
    stage_chunk(Ag, Bg, bk, bufA[0], bufB[0], wave, lane);

    int cur = 0;
    for (int i = 0; i < NCHPB_; ++i) {
        const int nxt = (cur + 1 == NBUF_) ? 0 : cur + 1;

        if (i + 1 < NCHPB_) {
            stage_chunk(Ag, Bg, bk + (i + 1) * NBLK_, bufA[nxt], bufB[nxt], wave, lane);
            __builtin_amdgcn_sched_barrier(0);
            // counted wait: leave only chunk i+1's loads (6/wave for waves 0,1;
            // 5 for waves 2,3) in flight; drains chunk i's loads and older atomics.
            if (wave < 2) asm volatile("s_waitcnt vmcnt(6)" ::: "memory");
            else          asm volatile("s_waitcnt vmcnt(5)" ::: "memory");
        } else {
            asm volatile("s_waitcnt vmcnt(0)" ::: "memory");
        }
        __builtin_amdgcn_sched_barrier(0);
        __builtin_amdgcn_s_barrier();
        __builtin_amdgcn_sched_barrier(0);

        const int ch = bk + i * NBLK_;
        const int tc = ch >> 4, s = ch & 15;

        if (wave < 2) {
            // wave w handles l-quad w*4 + (lane>>4), r = lane&15
            const int l = wave * 4 + (lane >> 4);
            const float2* Al = (const float2*)&bufA[cur][(size_t)l * (K_ * 128)];
            const float2* Bl = (const float2*)&bufB[cur][(size_t)l * 128];
            float abr = 0.f, abi = 0.f;
#pragma unroll
            for (int k = 0; k < K_; ++k) {
                float2 a  = Al[k * 16 + r];
                float2 bv = Bl[k * 128 + r];
                abr = fmaf(a.x, bv.x, abr); abr = fmaf(-a.y, bv.y, abr);
                abi = fmaf(a.x, bv.y, abi); abi = fmaf( a.y, bv.x, abi);
            }
            const int lg = s * LCHUNK_ + l;
            const float2 xv0 = x2s[lg];
            const float2 xv1 = x2s[L_ + lg];
            float acc[6];
            {
                float Re = xv0.x * abr - xv0.y * abi;
                float Im = xv0.x * abi + xv0.y * abr;
                acc[0] = Re; acc[1] = Im;
                acc[2] = sqrtf(fmaf(Re, Re, fmaf(Im, Im, EPS_)));
                Re = xv1.x * abr - xv1.y * abi;
                Im = xv1.x * abi + xv1.y * abr;
                acc[3] = Re; acc[4] = Im;
                acc[5] = sqrtf(fmaf(Re, Re, fmaf(Im, Im, EPS_)));
            }
            // butterfly over the 4 l's in this wave (lane bits 4,5)
#pragma unroll
            for (int j = 0; j < 6; ++j) acc[j] += __shfl_xor(acc[j], 16);
#pragma unroll
            for (int j = 0; j < 6; ++j) acc[j] += __shfl_xor(acc[j], 32);

            if (lane < 16) {
                float* p0 = &part[(((size_t)tc * B_ + 0) * RS_ + r) * 3];
                float* p1 = &part[(((size_t)tc * B_ + 1) * RS_ + r) * 3];
                atomicAdd(p0 + 0, acc[0]);
                atomicAdd(p0 + 1, acc[1]);
                atomicAdd(p0 + 2, acc[2]);
                atomicAdd(p1 + 0, acc[3]);
                atomicAdd(p1 + 1, acc[4]);
                atomicAdd(p1 + 2, acc[5]);
            }
        }
        cur = nxt;
    }
}

// ---------------- Kernel 2b: finalize -> tr ----------------------------------
__global__ __launch_bounds__(256) void k_tr_fin(const float* __restrict__ part,
                                                float2* __restrict__ tr2) {
    const int idx = blockIdx.x * blockDim.x + threadIdx.x;
    const int total = T_ * C_ * B_ * RS_;   // 17408
    if (idx >= total) return;
    const int r  = idx & 15;
    const int b  = (idx >> 4) & 1;
    const int tc = idx >> 5;

    const size_t base = (((size_t)tc * B_ + b) * RS_ + r) * 3;
    const float a0 = part[base + 0];
    const float a1 = part[base + 1];
    const float a2 = part[base + 2];
    const float inv = a2 / ((a2 + EPS_) * (float)L_);
    const int t = tc / C_, c = tc % C_;
    tr2[(((size_t)b * T_ + t) * C_ + c) * RS_ + r] = make_float2(a0 * inv, a1 * inv);
}

// ---------------- Kernel 3: apply_space (interp RT->H, complex combine) ------
__global__ __launch_bounds__(256) void k_out(const float2* __restrict__ space_i,
                                             const float2* __restrict__ space_j,
                                             const float2* __restrict__ tr2,
                                             float2* __restrict__ out) {
    const int half = B_ * C_ * RS_ * H_;   // 524288
    int idx = blockIdx.x * blockDim.x + threadIdx.x;
    if (idx >= 2 * half) return;
    const int which = (idx >= half) ? 1 : 0;
    int id = idx - which * half;

    const int h = id & (H_ - 1);
    int rest = id >> 10;
    const int r = rest & 15; rest >>= 4;
    const int c = rest & 15;
    const int b = rest >> 4;

    const float2* __restrict__ sp2 = which ? space_j : space_i;

    const size_t trb = (((size_t)b * T_) * C_ + c) * RS_ + r;
    const size_t trs = (size_t)C_ * RS_;

    const float2 sh = tr2[trb + (size_t)which * trs];

    float pos = (h + 0.5f) * (16.0f / 1024.0f) - 0.5f;
    pos = fminf(fmaxf(pos, 0.0f), 15.0f);
    const int i0 = (int)floorf(pos);
    const int i1 = min(i0 + 1, RT_ - 1);
    const float w = pos - (float)i0;

    const int tb = 2 + which * RT_;
    const float2 z0 = tr2[trb + (size_t)(tb + i0) * trs];
    const float2 z1 = tr2[trb + (size_t)(tb + i1) * trs];
    const float zx = z0.x * (1.0f - w) + z1.x * w;
    const float zy = z0.y * (1.0f - w) + z1.y * w;

    const float2 sv = sp2[((size_t)c * RS_ + r) * H_ + h];
    const float sx = sv.x + sh.x;
    const float sy = sv.y + sh.y;

    out[idx] = make_float2(sy * zy - sx * zx, sx * zy + sy * zx);
}

extern "C" void kernel_launch(void* const* d_in, const int* in_sizes, int n_in,
                              void* d_out, int out_size, void* d_ws, size_t ws_size,
                              hipStream_t stream) {
    const float* x  = (const float*)d_in[0];
    const float* Wc = (const float*)d_in[1];
    const float* bc = (const float*)d_in[2];
    const char*  Ag = (const char*)d_in[3];
    const char*  Bg = (const char*)d_in[4];
    const float2* si = (const float2*)d_in[5];
    const float2* sj = (const float2*)d_in[6];

    float2* x2   = (float2*)d_ws;                                  // 2 KB
    float*  part = (float*)((char*)d_ws + 4096);                   // 544*2*16*3*4 = 209 KB
    float2* tr2  = (float2*)((char*)d_ws + 4096 + 256 * 1024);     // 139 KB

    const size_t part_bytes = (size_t)T_ * C_ * B_ * RS_ * 3 * sizeof(float);
    hipMemsetAsync(part, 0, part_bytes, stream);

    k_ctx<<<B_, 512, 0, stream>>>(x, Wc, bc, x2);

    k_tr_part<<<NBLK_, 256, 0, stream>>>(Ag, Bg, x2, part);

    const int fin_total = T_ * C_ * B_ * RS_;
    k_tr_fin<<<(fin_total + 255) / 256, 256, 0, stream>>>(part, tr2);

    const int total = 2 * B_ * C_ * RS_ * H_;
    k_out<<<(total + 255) / 256, 256, 0, stream>>>(si, sj, tr2, (float2*)d_out);
}

// Round 6
// 69.297 us; speedup vs baseline: 1.1133x; 1.1133x over previous
//
#include <hip/hip_runtime.h>
#include <math.h>

#define B_   2
#define CTX_ 512
#define C_   16
#define RS_  16
#define RT_  16
#define T_   34      // 2 + 2*RT
#define L_   128
#define K_   11
#define H_   1024
#define EPS_ 1e-12f

#define NSPLIT_  16
#define LCHUNK_  8                       // L_ / NSPLIT_
#define NCHUNK_  (T_ * C_ * NSPLIT_)     // 8704
#define NBLK_    512                     // 2 blocks/CU * 256 CU
#define NCHPB_   17                      // NCHUNK_ / NBLK_  (exact)
#define CHUNKB_  (LCHUNK_ * K_ * 128)    // 11264 bytes per A (and per B) slice
#define NBUF_    3

__device__ __forceinline__ float siglog(float v) {
    return copysignf(log1pf(fabsf(v)), v);
}

__device__ __forceinline__ void gload_lds16(const void* g, void* l) {
    __builtin_amdgcn_global_load_lds(
        (const __attribute__((address_space(1))) unsigned int*)g,
        (__attribute__((address_space(3))) unsigned int*)l, 16, 0, 0);
}

// ---------------- Kernel 1: xt = x@W + b; xm; x2 = (xr+ixi)^2 ----------------
__global__ __launch_bounds__(512) void k_ctx(const float* __restrict__ x,
                                             const float* __restrict__ Wc,
                                             const float* __restrict__ bc,
                                             float2* __restrict__ x2out) {
    __shared__ float xrow[CTX_];
    __shared__ float xt[4 * L_];
    const int b = blockIdx.x;
    const int tid = threadIdx.x;
    xrow[tid] = x[b * CTX_ + tid];
    __syncthreads();
    float sum = bc[tid];
#pragma unroll 16
    for (int c = 0; c < CTX_; ++c)
        sum = fmaf(xrow[c], Wc[c * (4 * L_) + tid], sum);
    xt[tid] = sum;
    __syncthreads();
    if (tid < L_) {
        float xr = xt[2 * tid]     * siglog(xt[2 * L_ + 2 * tid]);
        float xi = xt[2 * tid + 1] * siglog(xt[2 * L_ + 2 * tid + 1]);
        x2out[b * L_ + tid] = make_float2(xr * xr - xi * xi, 2.0f * xr * xi);
    }
}

// ---------------- Kernel 2a: wave-specialized DMA-staged contraction ---------
// 512 blocks x 256 threads; block bk handles chunks bk + i*512, i in [0,17).
// Waves 2,3 = producers (wave2: A-segments, wave3: B-segments) -> their vmcnt
// FIFO holds ONLY chunk loads, so s_waitcnt vmcnt(11) counts the prefetch.
// Waves 0,1 = consumers (LDS compute + atomics) -> never wait on vmcnt, so
// atomic latency stays off the critical path. Triple buffer + one barrier/iter.
__device__ __forceinline__ void stage_A(const char* __restrict__ Ag, int ch,
                                        char* dst, int lane) {
    const int tc = ch >> 4, s = ch & 15;
    const char* Ab = Ag + (size_t)(tc * L_ + s * LCHUNK_) * (K_ * 128) + lane * 16;
#pragma unroll
    for (int id = 0; id < K_; ++id)
        gload_lds16(Ab + id * 1024, dst + id * 1024);
}

__device__ __forceinline__ void stage_B(const char* __restrict__ Bg, int ch,
                                        char* dst, int lane) {
    const int tc = ch >> 4, s = ch & 15;
    const char* Bb = Bg + (size_t)tc * (K_ * L_ * 128) + (size_t)s * (LCHUNK_ * 128)
                   + lane * 16;
#pragma unroll
    for (int k = 0; k < K_; ++k)
        gload_lds16(Bb + (size_t)k * (L_ * 128), dst + k * 1024);
}

__global__ __launch_bounds__(256) void k_tr_part(const char* __restrict__ Ag,
                                                 const char* __restrict__ Bg,
                                                 const float2* __restrict__ x2g,
                                                 float* __restrict__ part) {
    __shared__ __attribute__((aligned(16))) char bufA[NBUF_][CHUNKB_];
    __shared__ __attribute__((aligned(16))) char bufB[NBUF_][CHUNKB_];
    __shared__ float2 x2s[B_ * L_];

    const int tid  = threadIdx.x;
    const int wave = tid >> 6;
    const int lane = tid & 63;
    const int bk   = blockIdx.x;
    const int r    = lane & 15;

    // preload x2; compiler inserts vmcnt wait before ds_write, so every wave's
    // vmem FIFO is EMPTY after this point.
    x2s[tid] = x2g[tid];
    asm volatile("s_waitcnt lgkmcnt(0)" ::: "memory");

    // prologue: producers stage chunk 0 into buf 0
    if (wave == 2)      stage_A(Ag, bk, bufA[0], lane);
    else if (wave == 3) stage_B(Bg, bk, bufB[0], lane);

    int cur = 0;
    for (int i = 0; i < NCHPB_; ++i) {
        const int nxt = (cur + 1 == NBUF_) ? 0 : cur + 1;

        if (wave >= 2) {
            if (i + 1 < NCHPB_) {
                const int ch = bk + (i + 1) * NBLK_;
                if (wave == 2) stage_A(Ag, ch, bufA[nxt], lane);
                else           stage_B(Bg, ch, bufB[nxt], lane);
                __builtin_amdgcn_sched_barrier(0);
                // leave exactly chunk i+1's 11 loads in flight; drains chunk i
                asm volatile("s_waitcnt vmcnt(11)" ::: "memory");
            } else {
                asm volatile("s_waitcnt vmcnt(0)" ::: "memory");
            }
        }
        __builtin_amdgcn_sched_barrier(0);
        __builtin_amdgcn_s_barrier();
        __builtin_amdgcn_sched_barrier(0);

        if (wave < 2) {
            const int ch = bk + i * NBLK_;
            const int tc = ch >> 4, s = ch & 15;
            // wave w handles l-quad w*4 + (lane>>4), r = lane&15
            const int l = wave * 4 + (lane >> 4);
            const float2* Al = (const float2*)&bufA[cur][(size_t)l * (K_ * 128)];
            const float2* Bl = (const float2*)&bufB[cur][(size_t)l * 128];
            float abr = 0.f, abi = 0.f;
#pragma unroll
            for (int k = 0; k < K_; ++k) {
                float2 a  = Al[k * 16 + r];
                float2 bv = Bl[k * 128 + r];
                abr = fmaf(a.x, bv.x, abr); abr = fmaf(-a.y, bv.y, abr);
                abi = fmaf(a.x, bv.y, abi); abi = fmaf( a.y, bv.x, abi);
            }
            const int lg = s * LCHUNK_ + l;
            const float2 xv0 = x2s[lg];
            const float2 xv1 = x2s[L_ + lg];
            float acc[6];
            {
                float Re = xv0.x * abr - xv0.y * abi;
                float Im = xv0.x * abi + xv0.y * abr;
                acc[0] = Re; acc[1] = Im;
                acc[2] = sqrtf(fmaf(Re, Re, fmaf(Im, Im, EPS_)));
                Re = xv1.x * abr - xv1.y * abi;
                Im = xv1.x * abi + xv1.y * abr;
                acc[3] = Re; acc[4] = Im;
                acc[5] = sqrtf(fmaf(Re, Re, fmaf(Im, Im, EPS_)));
            }
            // butterfly over the 4 l's in this wave (lane bits 4,5)
#pragma unroll
            for (int j = 0; j < 6; ++j) acc[j] += __shfl_xor(acc[j], 16);
#pragma unroll
            for (int j = 0; j < 6; ++j) acc[j] += __shfl_xor(acc[j], 32);

            if (lane < 16) {
                float* p0 = &part[(((size_t)tc * B_ + 0) * RS_ + r) * 3];
                float* p1 = &part[(((size_t)tc * B_ + 1) * RS_ + r) * 3];
                atomicAdd(p0 + 0, acc[0]);
                atomicAdd(p0 + 1, acc[1]);
                atomicAdd(p0 + 2, acc[2]);
                atomicAdd(p1 + 0, acc[3]);
                atomicAdd(p1 + 1, acc[4]);
                atomicAdd(p1 + 2, acc[5]);
            }
        }
        cur = nxt;
    }
}

// ---------------- Kernel 2b: finalize -> tr ----------------------------------
__global__ __launch_bounds__(256) void k_tr_fin(const float* __restrict__ part,
                                                float2* __restrict__ tr2) {
    const int idx = blockIdx.x * blockDim.x + threadIdx.x;
    const int total = T_ * C_ * B_ * RS_;   // 17408
    if (idx >= total) return;
    const int r  = idx & 15;
    const int b  = (idx >> 4) & 1;
    const int tc = idx >> 5;

    const size_t base = (((size_t)tc * B_ + b) * RS_ + r) * 3;
    const float a0 = part[base + 0];
    const float a1 = part[base + 1];
    const float a2 = part[base + 2];
    const float inv = a2 / ((a2 + EPS_) * (float)L_);
    const int t = tc / C_, c = tc % C_;
    tr2[(((size_t)b * T_ + t) * C_ + c) * RS_ + r] = make_float2(a0 * inv, a1 * inv);
}

// ---------------- Kernel 3: apply_space (float4: 2 complex / thread) ---------
__global__ __launch_bounds__(256) void k_out(const float4* __restrict__ space_i4,
                                             const float4* __restrict__ space_j4,
                                             const float2* __restrict__ tr2,
                                             float4* __restrict__ out4) {
    const int halfq = B_ * C_ * RS_ * H_ / 2;   // 262144 float4 per output half
    int idx = blockIdx.x * blockDim.x + threadIdx.x;
    if (idx >= 2 * halfq) return;
    const int which = (idx >= halfq) ? 1 : 0;
    int id = idx - which * halfq;

    const int h2 = id & (H_ / 2 - 1);           // float4 index along h
    int rest = id >> 9;
    const int r = rest & 15; rest >>= 4;
    const int c = rest & 15;
    const int b = rest >> 4;

    const float4* __restrict__ sp4 = which ? space_j4 : space_i4;

    const size_t trb = (((size_t)b * T_) * C_ + c) * RS_ + r;
    const size_t trs = (size_t)C_ * RS_;

    const float2 sh = tr2[trb + (size_t)which * trs];
    const int tb = 2 + which * RT_;

    const float4 sv = sp4[((size_t)c * RS_ + r) * (H_ / 2) + h2];

    float res[4];
#pragma unroll
    for (int u = 0; u < 2; ++u) {
        const int h = 2 * h2 + u;
        float pos = (h + 0.5f) * (16.0f / 1024.0f) - 0.5f;
        pos = fminf(fmaxf(pos, 0.0f), 15.0f);
        const int i0 = (int)floorf(pos);
        const int i1 = min(i0 + 1, RT_ - 1);
        const float w = pos - (float)i0;

        const float2 z0 = tr2[trb + (size_t)(tb + i0) * trs];
        const float2 z1 = tr2[trb + (size_t)(tb + i1) * trs];
        const float zx = z0.x * (1.0f - w) + z1.x * w;
        const float zy = z0.y * (1.0f - w) + z1.y * w;

        const float sx = (u ? sv.z : sv.x) + sh.x;
        const float sy = (u ? sv.w : sv.y) + sh.y;

        res[2 * u + 0] = sy * zy - sx * zx;
        res[2 * u + 1] = sx * zy + sy * zx;
    }
    out4[idx] = make_float4(res[0], res[1], res[2], res[3]);
}

extern "C" void kernel_launch(void* const* d_in, const int* in_sizes, int n_in,
                              void* d_out, int out_size, void* d_ws, size_t ws_size,
                              hipStream_t stream) {
    const float* x  = (const float*)d_in[0];
    const float* Wc = (const float*)d_in[1];
    const float* bc = (const float*)d_in[2];
    const char*  Ag = (const char*)d_in[3];
    const char*  Bg = (const char*)d_in[4];
    const float4* si = (const float4*)d_in[5];
    const float4* sj = (const float4*)d_in[6];

    float2* x2   = (float2*)d_ws;                                  // 2 KB
    float*  part = (float*)((char*)d_ws + 4096);                   // 209 KB
    float2* tr2  = (float2*)((char*)d_ws + 4096 + 256 * 1024);     // 139 KB

    const size_t part_bytes = (size_t)T_ * C_ * B_ * RS_ * 3 * sizeof(float);
    hipMemsetAsync(part, 0, part_bytes, stream);

    k_ctx<<<B_, 512, 0, stream>>>(x, Wc, bc, x2);

    k_tr_part<<<NBLK_, 256, 0, stream>>>(Ag, Bg, x2, part);

    const int fin_total = T_ * C_ * B_ * RS_;
    k_tr_fin<<<(fin_total + 255) / 256, 256, 0, stream>>>(part, tr2);

    const int totalq = 2 * B_ * C_ * RS_ * H_ / 2;
    k_out<<<(totalq + 255) / 256, 256, 0, stream>>>(si, sj, tr2, (float4*)d_out);
}

// Round 7
// 65.633 us; speedup vs baseline: 1.1755x; 1.0558x over previous
//
#include <hip/hip_runtime.h>
#include <math.h>

#define B_   2
#define CTX_ 512
#define C_   16
#define RS_  16
#define RT_  16
#define T_   34      // 2 + 2*RT
#define L_   128
#define K_   11
#define H_   1024
#define EPS_ 1e-12f

#define NSPLIT_  16
#define LCHUNK_  8                       // L_ / NSPLIT_
#define NCHUNK_  (T_ * C_ * NSPLIT_)     // 8704 one-shot blocks
#define CHUNKB_  (LCHUNK_ * K_ * 128)    // 11264 bytes per A (and per B) slice
#define NLOAD_   22                      // 1KB DMA loads per chunk (11 A + 11 B)

__device__ __forceinline__ float siglog(float v) {
    return copysignf(log1pf(fabsf(v)), v);
}

__device__ __forceinline__ void gload_lds16(const void* g, void* l) {
    __builtin_amdgcn_global_load_lds(
        (const __attribute__((address_space(1))) unsigned int*)g,
        (__attribute__((address_space(3))) unsigned int*)l, 16, 0, 0);
}

// ---------------- Kernel 1: xt = x@W + b; xm; x2 = (xr+ixi)^2 ----------------
__global__ __launch_bounds__(512) void k_ctx(const float* __restrict__ x,
                                             const float* __restrict__ Wc,
                                             const float* __restrict__ bc,
                                             float2* __restrict__ x2out) {
    __shared__ float xrow[CTX_];
    __shared__ float xt[4 * L_];
    const int b = blockIdx.x;
    const int tid = threadIdx.x;
    xrow[tid] = x[b * CTX_ + tid];
    __syncthreads();
    float sum = bc[tid];
#pragma unroll 16
    for (int c = 0; c < CTX_; ++c)
        sum = fmaf(xrow[c], Wc[c * (4 * L_) + tid], sum);
    xt[tid] = sum;
    __syncthreads();
    if (tid < L_) {
        float xr = xt[2 * tid]     * siglog(xt[2 * L_ + 2 * tid]);
        float xi = xt[2 * tid + 1] * siglog(xt[2 * L_ + 2 * tid + 1]);
        x2out[b * L_ + tid] = make_float2(xr * xr - xi * xi, 2.0f * xr * xi);
    }
}

// ---------------- Kernel 2a: one-shot DMA-staged chunk contraction -----------
// 8704 blocks x 256 threads; block = one chunk (tc = blk>>4, s = blk&15):
// l in [s*8, s*8+8), all k, all r. All 4 waves stage 22 KB via global_load_lds,
// ONE __syncthreads (compiler drains vmcnt(0) -> race-free), waves 0,1 compute,
// atomics at exit. Latency hiding = ~7 resident blocks/CU rotating.
__global__ __launch_bounds__(256) void k_tr_chunk(const char* __restrict__ Ag,
                                                  const char* __restrict__ Bg,
                                                  const float2* __restrict__ x2g,
                                                  float* __restrict__ part) {
    __shared__ __attribute__((aligned(16))) char bufA[CHUNKB_];
    __shared__ __attribute__((aligned(16))) char bufB[CHUNKB_];

    const int tid  = threadIdx.x;
    const int wave = tid >> 6;
    const int lane = tid & 63;
    const int blk  = blockIdx.x;
    const int tc   = blk >> 4;
    const int s    = blk & 15;
    const int r    = lane & 15;
    const int l    = (wave & 1) * 4 + (lane >> 4);   // consumer mapping (wave<2)

    // stage 22 x 1KB: ids 0..10 = A k-slabs, 11..21 = B k-slabs
    {
        const char* Ab = Ag + (size_t)(tc * L_ + s * LCHUNK_) * (K_ * 128) + lane * 16;
        const char* Bb = Bg + (size_t)tc * (K_ * L_ * 128) + (size_t)s * (LCHUNK_ * 128)
                       + lane * 16;
        for (int id = wave; id < NLOAD_; id += 4) {
            if (id < K_) {
                gload_lds16(Ab + id * 1024, &bufA[id * 1024]);
            } else {
                const int k = id - K_;
                gload_lds16(Bb + (size_t)k * (L_ * 128), &bufB[k * 1024]);
            }
        }
    }

    // consumer-side tiny loads (L2-resident), overlapped with staging
    float2 xv0, xv1;
    if (wave < 2) {
        const int lg = s * LCHUNK_ + l;
        xv0 = x2g[lg];
        xv1 = x2g[L_ + lg];
    }

    __syncthreads();   // compiler emits s_waitcnt vmcnt(0) lgkmcnt(0) first

    if (wave < 2) {
        const float2* Al = (const float2*)&bufA[(size_t)l * (K_ * 128)];
        const float2* Bl = (const float2*)&bufB[(size_t)l * 128];
        float abr = 0.f, abi = 0.f;
#pragma unroll
        for (int k = 0; k < K_; ++k) {
            float2 a  = Al[k * 16 + r];
            float2 bv = Bl[k * 128 + r];
            abr = fmaf(a.x, bv.x, abr); abr = fmaf(-a.y, bv.y, abr);
            abi = fmaf(a.x, bv.y, abi); abi = fmaf( a.y, bv.x, abi);
        }
        float acc[6];
        {
            float Re = xv0.x * abr - xv0.y * abi;
            float Im = xv0.x * abi + xv0.y * abr;
            acc[0] = Re; acc[1] = Im;
            acc[2] = sqrtf(fmaf(Re, Re, fmaf(Im, Im, EPS_)));
            Re = xv1.x * abr - xv1.y * abi;
            Im = xv1.x * abi + xv1.y * abr;
            acc[3] = Re; acc[4] = Im;
            acc[5] = sqrtf(fmaf(Re, Re, fmaf(Im, Im, EPS_)));
        }
        // butterfly over the 4 l's in this wave (lane bits 4,5)
#pragma unroll
        for (int j = 0; j < 6; ++j) acc[j] += __shfl_xor(acc[j], 16);
#pragma unroll
        for (int j = 0; j < 6; ++j) acc[j] += __shfl_xor(acc[j], 32);

        if (lane < 16) {
            float* p0 = &part[(((size_t)tc * B_ + 0) * RS_ + r) * 3];
            float* p1 = &part[(((size_t)tc * B_ + 1) * RS_ + r) * 3];
            atomicAdd(p0 + 0, acc[0]);
            atomicAdd(p0 + 1, acc[1]);
            atomicAdd(p0 + 2, acc[2]);
            atomicAdd(p1 + 0, acc[3]);
            atomicAdd(p1 + 1, acc[4]);
            atomicAdd(p1 + 2, acc[5]);
        }
    }
}

// ---------------- Kernel 2b: finalize -> tr ----------------------------------
__global__ __launch_bounds__(256) void k_tr_fin(const float* __restrict__ part,
                                                float2* __restrict__ tr2) {
    const int idx = blockIdx.x * blockDim.x + threadIdx.x;
    const int total = T_ * C_ * B_ * RS_;   // 17408
    if (idx >= total) return;
    const int r  = idx & 15;
    const int b  = (idx >> 4) & 1;
    const int tc = idx >> 5;

    const size_t base = (((size_t)tc * B_ + b) * RS_ + r) * 3;
    const float a0 = part[base + 0];
    const float a1 = part[base + 1];
    const float a2 = part[base + 2];
    const float inv = a2 / ((a2 + EPS_) * (float)L_);
    const int t = tc / C_, c = tc % C_;
    tr2[(((size_t)b * T_ + t) * C_ + c) * RS_ + r] = make_float2(a0 * inv, a1 * inv);
}

// ---------------- Kernel 3: apply_space (float4: 2 complex / thread) ---------
__global__ __launch_bounds__(256) void k_out(const float4* __restrict__ space_i4,
                                             const float4* __restrict__ space_j4,
                                             const float2* __restrict__ tr2,
                                             float4* __restrict__ out4) {
    const int halfq = B_ * C_ * RS_ * H_ / 2;   // 262144 float4 per output half
    int idx = blockIdx.x * blockDim.x + threadIdx.x;
    if (idx >= 2 * halfq) return;
    const int which = (idx >= halfq) ? 1 : 0;
    int id = idx - which * halfq;

    const int h2 = id & (H_ / 2 - 1);           // float4 index along h
    int rest = id >> 9;
    const int r = rest & 15; rest >>= 4;
    const int c = rest & 15;
    const int b = rest >> 4;

    const float4* __restrict__ sp4 = which ? space_j4 : space_i4;

    const size_t trb = (((size_t)b * T_) * C_ + c) * RS_ + r;
    const size_t trs = (size_t)C_ * RS_;

    const float2 sh = tr2[trb + (size_t)which * trs];
    const int tb = 2 + which * RT_;

    const float4 sv = sp4[((size_t)c * RS_ + r) * (H_ / 2) + h2];

    float res[4];
#pragma unroll
    for (int u = 0; u < 2; ++u) {
        const int h = 2 * h2 + u;
        float pos = (h + 0.5f) * (16.0f / 1024.0f) - 0.5f;
        pos = fminf(fmaxf(pos, 0.0f), 15.0f);
        const int i0 = (int)floorf(pos);
        const int i1 = min(i0 + 1, RT_ - 1);
        const float w = pos - (float)i0;

        const float2 z0 = tr2[trb + (size_t)(tb + i0) * trs];
        const float2 z1 = tr2[trb + (size_t)(tb + i1) * trs];
        const float zx = z0.x * (1.0f - w) + z1.x * w;
        const float zy = z0.y * (1.0f - w) + z1.y * w;

        const float sx = (u ? sv.z : sv.x) + sh.x;
        const float sy = (u ? sv.w : sv.y) + sh.y;

        res[2 * u + 0] = sy * zy - sx * zx;
        res[2 * u + 1] = sx * zy + sy * zx;
    }
    out4[idx] = make_float4(res[0], res[1], res[2], res[3]);
}

extern "C" void kernel_launch(void* const* d_in, const int* in_sizes, int n_in,
                              void* d_out, int out_size, void* d_ws, size_t ws_size,
                              hipStream_t stream) {
    const float* x  = (const float*)d_in[0];
    const float* Wc = (const float*)d_in[1];
    const float* bc = (const float*)d_in[2];
    const char*  Ag = (const char*)d_in[3];
    const char*  Bg = (const char*)d_in[4];
    const float4* si = (const float4*)d_in[5];
    const float4* sj = (const float4*)d_in[6];

    float2* x2   = (float2*)d_ws;                                  // 2 KB
    float*  part = (float*)((char*)d_ws + 4096);                   // 209 KB
    float2* tr2  = (float2*)((char*)d_ws + 4096 + 256 * 1024);     // 139 KB

    const size_t part_bytes = (size_t)T_ * C_ * B_ * RS_ * 3 * sizeof(float);
    hipMemsetAsync(part, 0, part_bytes, stream);

    k_ctx<<<B_, 512, 0, stream>>>(x, Wc, bc, x2);

    k_tr_chunk<<<NCHUNK_, 256, 0, stream>>>(Ag, Bg, x2, part);

    const int fin_total = T_ * C_ * B_ * RS_;
    k_tr_fin<<<(fin_total + 255) / 256, 256, 0, stream>>>(part, tr2);

    const int totalq = 2 * B_ * C_ * RS_ * H_ / 2;
    k_out<<<(totalq + 255) / 256, 256, 0, stream>>>(si, sj, tr2, (float4*)d_out);
}

// Round 9
// 63.388 us; speedup vs baseline: 1.2171x; 1.0354x over previous
//
#include <hip/hip_runtime.h>
#include <math.h>

#define B_   2
#define CTX_ 512
#define C_   16
#define RS_  16
#define RT_  16
#define T_   34      // 2 + 2*RT
#define L_   128
#define K_   11
#define H_   1024
#define EPS_ 1e-12f

#define NSPLIT_  16
#define LCHUNK_  8                       // L_ / NSPLIT_
#define NCHUNK_  (T_ * C_ * NSPLIT_)     // 8704 one-shot blocks
#define CHUNKB_  (LCHUNK_ * K_ * 128)    // 11264 bytes per A (and per B) slice
#define NLOAD_   22                      // 1KB DMA loads per chunk (11 A + 11 B)

typedef float vfloat4 __attribute__((ext_vector_type(4)));

__device__ __forceinline__ float siglog(float v) {
    return copysignf(log1pf(fabsf(v)), v);
}

__device__ __forceinline__ void gload_lds16(const void* g, void* l) {
    __builtin_amdgcn_global_load_lds(
        (const __attribute__((address_space(1))) unsigned int*)g,
        (__attribute__((address_space(3))) unsigned int*)l, 16, 0, 0);
}

// ---------------- Kernel 1: xt = x@W + b; xm; x2 = (xr+ixi)^2 ----------------
__global__ __launch_bounds__(512) void k_ctx(const float* __restrict__ x,
                                             const float* __restrict__ Wc,
                                             const float* __restrict__ bc,
                                             float2* __restrict__ x2out) {
    __shared__ float xrow[CTX_];
    __shared__ float xt[4 * L_];
    const int b = blockIdx.x;
    const int tid = threadIdx.x;
    xrow[tid] = x[b * CTX_ + tid];
    __syncthreads();
    float sum = bc[tid];
#pragma unroll 16
    for (int c = 0; c < CTX_; ++c)
        sum = fmaf(xrow[c], Wc[c * (4 * L_) + tid], sum);
    xt[tid] = sum;
    __syncthreads();
    if (tid < L_) {
        float xr = xt[2 * tid]     * siglog(xt[2 * L_ + 2 * tid]);
        float xi = xt[2 * tid + 1] * siglog(xt[2 * L_ + 2 * tid + 1]);
        x2out[b * L_ + tid] = make_float2(xr * xr - xi * xi, 2.0f * xr * xi);
    }
}

// ---------------- Kernel 2: one-shot DMA-staged chunk contraction ------------
// 8704 blocks x 256 threads; block = one chunk (tc = blk>>4, s = blk&15).
// All 4 waves stage 22 KB via global_load_lds, one __syncthreads (compiler
// drains vmcnt(0) -> race-free), waves 0,1 compute + atomics.
__global__ __launch_bounds__(256) void k_tr_chunk(const char* __restrict__ Ag,
                                                  const char* __restrict__ Bg,
                                                  const float2* __restrict__ x2g,
                                                  float* __restrict__ part) {
    __shared__ __attribute__((aligned(16))) char bufA[CHUNKB_];
    __shared__ __attribute__((aligned(16))) char bufB[CHUNKB_];

    const int tid  = threadIdx.x;
    const int wave = tid >> 6;
    const int lane = tid & 63;
    const int blk  = blockIdx.x;
    const int tc   = blk >> 4;
    const int s    = blk & 15;
    const int r    = lane & 15;
    const int l    = (wave & 1) * 4 + (lane >> 4);   // consumer mapping (wave<2)

    // stage 22 x 1KB: ids 0..10 = A k-slabs, 11..21 = B k-slabs
    {
        const char* Ab = Ag + (size_t)(tc * L_ + s * LCHUNK_) * (K_ * 128) + lane * 16;
        const char* Bb = Bg + (size_t)tc * (K_ * L_ * 128) + (size_t)s * (LCHUNK_ * 128)
                       + lane * 16;
        for (int id = wave; id < NLOAD_; id += 4) {
            if (id < K_) {
                gload_lds16(Ab + id * 1024, &bufA[id * 1024]);
            } else {
                const int k = id - K_;
                gload_lds16(Bb + (size_t)k * (L_ * 128), &bufB[k * 1024]);
            }
        }
    }

    // consumer-side tiny loads (L2-resident), overlapped with staging
    float2 xv0, xv1;
    if (wave < 2) {
        const int lg = s * LCHUNK_ + l;
        xv0 = x2g[lg];
        xv1 = x2g[L_ + lg];
    }

    __syncthreads();   // compiler emits s_waitcnt vmcnt(0) lgkmcnt(0) first

    if (wave < 2) {
        const float2* Al = (const float2*)&bufA[(size_t)l * (K_ * 128)];
        const float2* Bl = (const float2*)&bufB[(size_t)l * 128];
        float abr = 0.f, abi = 0.f;
#pragma unroll
        for (int k = 0; k < K_; ++k) {
            float2 a  = Al[k * 16 + r];
            float2 bv = Bl[k * 128 + r];
            abr = fmaf(a.x, bv.x, abr); abr = fmaf(-a.y, bv.y, abr);
            abi = fmaf(a.x, bv.y, abi); abi = fmaf( a.y, bv.x, abi);
        }
        float acc[6];
        {
            float Re = xv0.x * abr - xv0.y * abi;
            float Im = xv0.x * abi + xv0.y * abr;
            acc[0] = Re; acc[1] = Im;
            acc[2] = sqrtf(fmaf(Re, Re, fmaf(Im, Im, EPS_)));
            Re = xv1.x * abr - xv1.y * abi;
            Im = xv1.x * abi + xv1.y * abr;
            acc[3] = Re; acc[4] = Im;
            acc[5] = sqrtf(fmaf(Re, Re, fmaf(Im, Im, EPS_)));
        }
        // butterfly over the 4 l's in this wave (lane bits 4,5)
#pragma unroll
        for (int j = 0; j < 6; ++j) acc[j] += __shfl_xor(acc[j], 16);
#pragma unroll
        for (int j = 0; j < 6; ++j) acc[j] += __shfl_xor(acc[j], 32);

        if (lane < 16) {
            float* p0 = &part[(((size_t)tc * B_ + 0) * RS_ + r) * 3];
            float* p1 = &part[(((size_t)tc * B_ + 1) * RS_ + r) * 3];
            atomicAdd(p0 + 0, acc[0]);
            atomicAdd(p0 + 1, acc[1]);
            atomicAdd(p0 + 2, acc[2]);
            atomicAdd(p1 + 0, acc[3]);
            atomicAdd(p1 + 1, acc[4]);
            atomicAdd(p1 + 2, acc[5]);
        }
    }
}

// ---------------- Kernel 3: fused finalize + apply_space ---------------------
// Reads raw partials (L2-hot, 209 KB) and finalizes tr inline; output stores
// are NON-TEMPORAL so the 16.8 MB write stream doesn't churn A/B out of L3.
__device__ __forceinline__ float2 tr_at(const float* __restrict__ part,
                                        int t, int c, int b, int r) {
    const int tc = t * C_ + c;
    const size_t base = (((size_t)tc * B_ + b) * RS_ + r) * 3;
    const float a0 = part[base + 0];
    const float a1 = part[base + 1];
    const float a2 = part[base + 2];
    const float inv = a2 / ((a2 + EPS_) * (float)L_);
    return make_float2(a0 * inv, a1 * inv);
}

__global__ __launch_bounds__(256) void k_out(const float4* __restrict__ space_i4,
                                             const float4* __restrict__ space_j4,
                                             const float* __restrict__ part,
                                             float4* __restrict__ out4) {
    const int halfq = B_ * C_ * RS_ * H_ / 2;   // 262144 float4 per output half
    int idx = blockIdx.x * blockDim.x + threadIdx.x;
    if (idx >= 2 * halfq) return;
    const int which = (idx >= halfq) ? 1 : 0;
    int id = idx - which * halfq;

    const int h2 = id & (H_ / 2 - 1);           // float4 index along h
    int rest = id >> 9;
    const int r = rest & 15; rest >>= 4;
    const int c = rest & 15;
    const int b = rest >> 4;

    const float4* __restrict__ sp4 = which ? space_j4 : space_i4;

    const float2 sh = tr_at(part, which, c, b, r);
    const int tb = 2 + which * RT_;

    const float4 sv = sp4[((size_t)c * RS_ + r) * (H_ / 2) + h2];

    float res[4];
#pragma unroll
    for (int u = 0; u < 2; ++u) {
        const int h = 2 * h2 + u;
        float pos = (h + 0.5f) * (16.0f / 1024.0f) - 0.5f;
        pos = fminf(fmaxf(pos, 0.0f), 15.0f);
        const int i0 = (int)floorf(pos);
        const int i1 = min(i0 + 1, RT_ - 1);
        const float w = pos - (float)i0;

        const float2 z0 = tr_at(part, tb + i0, c, b, r);
        const float2 z1 = tr_at(part, tb + i1, c, b, r);
        const float zx = z0.x * (1.0f - w) + z1.x * w;
        const float zy = z0.y * (1.0f - w) + z1.y * w;

        const float sx = (u ? sv.z : sv.x) + sh.x;
        const float sy = (u ? sv.w : sv.y) + sh.y;

        res[2 * u + 0] = sy * zy - sx * zx;
        res[2 * u + 1] = sx * zy + sy * zx;
    }
    vfloat4 rv;
    rv.x = res[0]; rv.y = res[1]; rv.z = res[2]; rv.w = res[3];
    __builtin_nontemporal_store(rv, (vfloat4*)&out4[idx]);
}

extern "C" void kernel_launch(void* const* d_in, const int* in_sizes, int n_in,
                              void* d_out, int out_size, void* d_ws, size_t ws_size,
                              hipStream_t stream) {
    const float* x  = (const float*)d_in[0];
    const float* Wc = (const float*)d_in[1];
    const float* bc = (const float*)d_in[2];
    const char*  Ag = (const char*)d_in[3];
    const char*  Bg = (const char*)d_in[4];
    const float4* si = (const float4*)d_in[5];
    const float4* sj = (const float4*)d_in[6];

    float2* x2   = (float2*)d_ws;                                  // 2 KB
    float*  part = (float*)((char*)d_ws + 4096);                   // 209 KB

    const size_t part_bytes = (size_t)T_ * C_ * B_ * RS_ * 3 * sizeof(float);
    (void)hipMemsetAsync(part, 0, part_bytes, stream);

    k_ctx<<<B_, 512, 0, stream>>>(x, Wc, bc, x2);

    k_tr_chunk<<<NCHUNK_, 256, 0, stream>>>(Ag, Bg, x2, part);

    const int totalq = 2 * B_ * C_ * RS_ * H_ / 2;
    k_out<<<(totalq + 255) / 256, 256, 0, stream>>>(si, sj, part, (float4*)d_out);
}

// Round 10
// 59.061 us; speedup vs baseline: 1.3063x; 1.0733x over previous
//
#include <hip/hip_runtime.h>
#include <math.h>

#define B_   2
#define CTX_ 512
#define C_   16
#define RS_  16
#define RT_  16
#define T_   34      // 2 + 2*RT
#define L_   128
#define K_   11
#define H_   1024
#define EPS_ 1e-12f

#define NSPLIT_  4
#define LCHUNK_  32                      // L_ / NSPLIT_
#define NBLKTR_  (T_ * C_ * NSPLIT_)     // 2176

typedef float vfloat4 __attribute__((ext_vector_type(4)));

__device__ __forceinline__ float siglog(float v) {
    return copysignf(log1pf(fabsf(v)), v);
}

// ---------------- Kernel 1: xt = x@W + b; xm; x2 = (xr+ixi)^2 ----------------
__global__ __launch_bounds__(512) void k_ctx(const float* __restrict__ x,
                                             const float* __restrict__ Wc,
                                             const float* __restrict__ bc,
                                             float2* __restrict__ x2out) {
    __shared__ float xrow[CTX_];
    __shared__ float xt[4 * L_];
    const int b = blockIdx.x;
    const int tid = threadIdx.x;
    xrow[tid] = x[b * CTX_ + tid];
    __syncthreads();
    float sum = bc[tid];
#pragma unroll 16
    for (int c = 0; c < CTX_; ++c)
        sum = fmaf(xrow[c], Wc[c * (4 * L_) + tid], sum);
    xt[tid] = sum;
    __syncthreads();
    if (tid < L_) {
        float xr = xt[2 * tid]     * siglog(xt[2 * L_ + 2 * tid]);
        float xi = xt[2 * tid + 1] * siglog(xt[2 * L_ + 2 * tid + 1]);
        x2out[b * L_ + tid] = make_float2(xr * xr - xi * xi, 2.0f * xr * xi);
    }
}

// ---------------- Kernel 2: register-staged contraction, forced MLP ----------
// 2176 blocks x 256 threads; block = (tc = blk>>2, s = blk&3), 32 l's.
// Thread = (l = s*32 + tid>>3, r-pair = tid&7). ALL 24 vmem reads (11 A +
// 11 B float4 + 2 x2) are pinned BEFORE any compute by a hard
// sched_barrier(0); launch_bounds(256,2) gives regalloc room (~120 VGPR)
// so all 22 data loads stay in flight per thread.
__global__ __launch_bounds__(256, 2) void k_tr_part(const float4* __restrict__ A4,
                                                    const float4* __restrict__ B4,
                                                    const float2* __restrict__ x2g,
                                                    float* __restrict__ part) {
    const int blk = blockIdx.x;
    const int tc  = blk >> 2;
    const int s   = blk & 3;
    const int tid = threadIdx.x;
    const int rp  = tid & 7;
    const int l   = s * LCHUNK_ + (tid >> 3);

    const float4* __restrict__ Ab = A4 + ((size_t)(tc * L_ + l) * K_) * 8 + rp;
    const float4* __restrict__ Bb = B4 + ((size_t)tc * K_ * L_ + l) * 8 + rp;

    float4 a[K_];
    float4 bv[K_];
#pragma unroll
    for (int k = 0; k < K_; ++k) a[k]  = Ab[(size_t)k * 8];
#pragma unroll
    for (int k = 0; k < K_; ++k) bv[k] = Bb[(size_t)k * L_ * 8];
    const float2 xv0 = x2g[l];
    const float2 xv1 = x2g[L_ + l];

    // HARD pin: nothing below may be scheduled above this point -> all 24
    // loads are issued back-to-back before the first FMA.
    __builtin_amdgcn_sched_barrier(0);

    float abr0 = 0.f, abi0 = 0.f, abr1 = 0.f, abi1 = 0.f;
#pragma unroll
    for (int k = 0; k < K_; ++k) {
        abr0 = fmaf(a[k].x, bv[k].x, abr0); abr0 = fmaf(-a[k].y, bv[k].y, abr0);
        abi0 = fmaf(a[k].x, bv[k].y, abi0); abi0 = fmaf( a[k].y, bv[k].x, abi0);
        abr1 = fmaf(a[k].z, bv[k].z, abr1); abr1 = fmaf(-a[k].w, bv[k].w, abr1);
        abi1 = fmaf(a[k].z, bv[k].w, abi1); abi1 = fmaf( a[k].w, bv[k].z, abi1);
    }

    // 12 accumulators: [b][pair][{Re,Im,M}]
    float acc[12];
    {
        float Re0 = xv0.x * abr0 - xv0.y * abi0;
        float Im0 = xv0.x * abi0 + xv0.y * abr0;
        float Re1 = xv0.x * abr1 - xv0.y * abi1;
        float Im1 = xv0.x * abi1 + xv0.y * abr1;
        acc[0] = Re0; acc[1] = Im0;
        acc[2] = sqrtf(fmaf(Re0, Re0, fmaf(Im0, Im0, EPS_)));
        acc[3] = Re1; acc[4] = Im1;
        acc[5] = sqrtf(fmaf(Re1, Re1, fmaf(Im1, Im1, EPS_)));
    }
    {
        float Re0 = xv1.x * abr0 - xv1.y * abi0;
        float Im0 = xv1.x * abi0 + xv1.y * abr0;
        float Re1 = xv1.x * abr1 - xv1.y * abi1;
        float Im1 = xv1.x * abi1 + xv1.y * abr1;
        acc[6] = Re0; acc[7] = Im0;
        acc[8] = sqrtf(fmaf(Re0, Re0, fmaf(Im0, Im0, EPS_)));
        acc[9] = Re1; acc[10] = Im1;
        acc[11] = sqrtf(fmaf(Re1, Re1, fmaf(Im1, Im1, EPS_)));
    }

    // butterfly over the 8 l's within the wave (lane bits 3,4,5)
#pragma unroll
    for (int off = 8; off <= 32; off <<= 1) {
#pragma unroll
        for (int i = 0; i < 12; ++i)
            acc[i] += __shfl_xor(acc[i], off);
    }

    __shared__ float wred[4][8][12];
    const int wave = tid >> 6;
    const int lane = tid & 63;
    if (lane < 8) {
#pragma unroll
        for (int i = 0; i < 12; ++i) wred[wave][lane][i] = acc[i];
    }
    __syncthreads();

    // 96 outputs: comp = (b*2+pair)*3 + c3, r = 2*rpi + pair
    if (tid < 96) {
        const int rpi  = tid / 12;          // 0..7
        const int comp = tid % 12;
        float v = wred[0][rpi][comp] + wred[1][rpi][comp]
                + wred[2][rpi][comp] + wred[3][rpi][comp];
        const int b    = comp / 6;
        const int pair = (comp / 3) & 1;
        const int c3   = comp % 3;
        const int r    = 2 * rpi + pair;
        atomicAdd(&part[(((size_t)tc * B_ + b) * RS_ + r) * 3 + c3], v);
    }
}

// ---------------- Kernel 3: fused finalize + apply_space ---------------------
__device__ __forceinline__ float2 tr_at(const float* __restrict__ part,
                                        int t, int c, int b, int r) {
    const int tc = t * C_ + c;
    const size_t base = (((size_t)tc * B_ + b) * RS_ + r) * 3;
    const float a0 = part[base + 0];
    const float a1 = part[base + 1];
    const float a2 = part[base + 2];
    const float inv = a2 / ((a2 + EPS_) * (float)L_);
    return make_float2(a0 * inv, a1 * inv);
}

__global__ __launch_bounds__(256) void k_out(const float4* __restrict__ space_i4,
                                             const float4* __restrict__ space_j4,
                                             const float* __restrict__ part,
                                             float4* __restrict__ out4) {
    const int halfq = B_ * C_ * RS_ * H_ / 2;   // 262144 float4 per output half
    int idx = blockIdx.x * blockDim.x + threadIdx.x;
    if (idx >= 2 * halfq) return;
    const int which = (idx >= halfq) ? 1 : 0;
    int id = idx - which * halfq;

    const int h2 = id & (H_ / 2 - 1);           // float4 index along h
    int rest = id >> 9;
    const int r = rest & 15; rest >>= 4;
    const int c = rest & 15;
    const int b = rest >> 4;

    const float4* __restrict__ sp4 = which ? space_j4 : space_i4;

    const float2 sh = tr_at(part, which, c, b, r);
    const int tb = 2 + which * RT_;

    const float4 sv = sp4[((size_t)c * RS_ + r) * (H_ / 2) + h2];

    float res[4];
#pragma unroll
    for (int u = 0; u < 2; ++u) {
        const int h = 2 * h2 + u;
        float pos = (h + 0.5f) * (16.0f / 1024.0f) - 0.5f;
        pos = fminf(fmaxf(pos, 0.0f), 15.0f);
        const int i0 = (int)floorf(pos);
        const int i1 = min(i0 + 1, RT_ - 1);
        const float w = pos - (float)i0;

        const float2 z0 = tr_at(part, tb + i0, c, b, r);
        const float2 z1 = tr_at(part, tb + i1, c, b, r);
        const float zx = z0.x * (1.0f - w) + z1.x * w;
        const float zy = z0.y * (1.0f - w) + z1.y * w;

        const float sx = (u ? sv.z : sv.x) + sh.x;
        const float sy = (u ? sv.w : sv.y) + sh.y;

        res[2 * u + 0] = sy * zy - sx * zx;
        res[2 * u + 1] = sx * zy + sy * zx;
    }
    vfloat4 rv;
    rv.x = res[0]; rv.y = res[1]; rv.z = res[2]; rv.w = res[3];
    __builtin_nontemporal_store(rv, (vfloat4*)&out4[idx]);
}

extern "C" void kernel_launch(void* const* d_in, const int* in_sizes, int n_in,
                              void* d_out, int out_size, void* d_ws, size_t ws_size,
                              hipStream_t stream) {
    const float*  x  = (const float*)d_in[0];
    const float*  Wc = (const float*)d_in[1];
    const float*  bc = (const float*)d_in[2];
    const float4* A4 = (const float4*)d_in[3];
    const float4* B4 = (const float4*)d_in[4];
    const float4* si = (const float4*)d_in[5];
    const float4* sj = (const float4*)d_in[6];

    float2* x2   = (float2*)d_ws;                                  // 2 KB
    float*  part = (float*)((char*)d_ws + 4096);                   // 209 KB

    const size_t part_bytes = (size_t)T_ * C_ * B_ * RS_ * 3 * sizeof(float);
    (void)hipMemsetAsync(part, 0, part_bytes, stream);

    k_ctx<<<B_, 512, 0, stream>>>(x, Wc, bc, x2);

    k_tr_part<<<NBLKTR_, 256, 0, stream>>>(A4, B4, x2, part);

    const int totalq = 2 * B_ * C_ * RS_ * H_ / 2;
    k_out<<<(totalq + 255) / 256, 256, 0, stream>>>(si, sj, part, (float4*)d_out);
}